// Round 2
// baseline (299.552 us; speedup 1.0000x reference)
//
#include <hip/hip_runtime.h>

// SSIM loss, fused. Round 8: wave-autonomous bands + FORCED software pipeline.
//  - r7 POST-MORTEM: VGPR_Count=56 proved the compiler discarded the prefetch
//    (needs >=64 live regs) and sank loads to uses -> every iteration exposed
//    full L3/HBM latency serially (VALUBusy 21%). Fix: restructure so each
//    load's issue->use distance is one full loop body, and pin issue points
//    with __builtin_amdgcn_sched_barrier(0) so the scheduler cannot sink them.
//  - Iteration: add(new,waits nx) -> issue next-new -> SB -> shfl/W-chain ->
//    subtract(retire,waits rx) -> issue next-retire -> SB -> ssim x8.
//    Steady state: 8 loads in flight, all waits are counted vmcnt(4),
//    each load has ~600-800 cyc of shadow.
//  - Everything else as r7: 64-lane wave owns full 512-col x 11-row band,
//    8 cols/lane, 4 register sum planes (Sx,Sy,Sxx+Syy,Sxy), halo via 6
//    shfl_down per plane, no LDS in hot loop, no barriers.

#define IW    512
#define OUTW  506
#define BAND  11                 // output rows per wave; 46*11 = 506 exactly
#define NBANDS 46
#define NIMG  96
#define WPB   4                  // independent waves per block
#define NBLK  (NBANDS * NIMG / WPB)   // 1104 blocks
#define NPART NBLK
#define C1N2  0.2401f            // 1e-4 * 49^2
#define C2N2  2.1609f            // 9e-4 * 49^2
#define KA    (49.0f/24.0f)
#define KB    (49.0f/48.0f)
#define TOTAL_OUT 24579456.0f    // 96*506*506

__device__ __forceinline__ float ssim_raw(float Sx, float Sy, float S2, float Sxy) {
    float sxsy = Sx * Sy;
    float p    = fmaf(Sx, Sx, Sy * Sy);
    float a1   = fmaf(2.0f, sxsy, C1N2);
    float b1   = p + C1N2;
    float a2   = fmaf(KA, fmaf(49.0f, Sxy, -sxsy), C2N2);
    float b2   = fmaf(KB, fmaf(49.0f, S2, -p), C2N2);
    return (a1 * a2) * __builtin_amdgcn_rcpf(b1 * b2);
}

__device__ __forceinline__ void unpack8(float4 a, float4 b, float* d) {
    d[0]=a.x; d[1]=a.y; d[2]=a.z; d[3]=a.w;
    d[4]=b.x; d[5]=b.y; d[6]=b.z; d[7]=b.w;
}

__global__ __launch_bounds__(256, 4) void ssim_main(const float* __restrict__ X,
                                                    const float* __restrict__ Y,
                                                    float* __restrict__ partials) {
    __shared__ float wsum[WPB];
    const int t    = threadIdx.x;
    const int wv   = t >> 6;
    const int lane = t & 63;
    const int gw   = blockIdx.x * WPB + wv;      // 0..4415
    const int img  = gw / NBANDS;
    const int band = gw - img * NBANDS;
    const int r0   = band * BAND;
    const float4* X4 = (const float4*)X + (size_t)img * (IW * IW / 4);
    const float4* Y4 = (const float4*)Y + (size_t)img * (IW * IW / 4);
    const int c0 = 2 * lane;                     // float4 index of col 8*lane

    // vertical sliding column sums, 8 cols/lane, 4 planes = 32 VGPR
    float sx[8], sy[8], s2[8], sxy[8];
#pragma unroll
    for (int q = 0; q < 8; ++q) { sx[q]=0.f; sy[q]=0.f; s2[q]=0.f; sxy[q]=0.f; }

    // prologue: rows r0 .. r0+5 (24 independent loads, one latency trip)
#pragma unroll
    for (int i = 0; i < 6; ++i) {
        const int ro = (r0 + i) * (IW / 4);
        float4 xa = X4[ro + c0], xb = X4[ro + c0 + 1];
        float4 ya = Y4[ro + c0], yb = Y4[ro + c0 + 1];
        float x[8], y[8];
        unpack8(xa, xb, x); unpack8(ya, yb, y);
#pragma unroll
        for (int q = 0; q < 8; ++q) {
            sx[q] += x[q]; sy[q] += y[q];
            s2[q]  = fmaf(x[q], x[q], s2[q]);
            s2[q]  = fmaf(y[q], y[q], s2[q]);
            sxy[q] = fmaf(x[q], y[q], sxy[q]);
        }
    }

    // prefetch for r=0: new row r0+6, retire row r0
    {
        const int rn = (r0 + 6) * (IW / 4);
        const int rr = r0 * (IW / 4);
        // declared below; issue here via first-iteration values
    }
    int rnaddr = (r0 + 6) * (IW / 4);
    float4 nxa = X4[rnaddr + c0], nxb = X4[rnaddr + c0 + 1];
    float4 nya = Y4[rnaddr + c0], nyb = Y4[rnaddr + c0 + 1];
    int rraddr = r0 * (IW / 4);
    float4 rxa = X4[rraddr + c0], rxb = X4[rraddr + c0 + 1];
    float4 rya = Y4[rraddr + c0], ryb = Y4[rraddr + c0 + 1];

    float accS = 0.0f;

#pragma unroll 1
    for (int r = 0; r < BAND; ++r) {
        // ---- 1. vertical add of prefetched new row (waits nx: vmcnt(4)) ----
        {
            float x[8], y[8];
            unpack8(nxa, nxb, x); unpack8(nya, nyb, y);
#pragma unroll
            for (int q = 0; q < 8; ++q) {
                sx[q] += x[q]; sy[q] += y[q];
                s2[q]  = fmaf(x[q], x[q], s2[q]);
                s2[q]  = fmaf(y[q], y[q], s2[q]);
                sxy[q] = fmaf(x[q], y[q], sxy[q]);
            }
        }
        // ---- 2. issue next new-row loads (regs just died; full-iter shadow)
        {
            const int rn = min(r0 + 7 + r, IW - 1) * (IW / 4);  // clamp: last iter value unused
            nxa = X4[rn + c0]; nxb = X4[rn + c0 + 1];
            nya = Y4[rn + c0]; nyb = Y4[rn + c0 + 1];
        }
        __builtin_amdgcn_sched_barrier(0);   // pin issue point: no sinking

        // ---- 3. horizontal 7-windows: halo = next lane's first 6 col sums
        float Wx[8], Wy[8], W2[8], Wxy[8];
#define HWIN(S, W)                                                         \
        {                                                                  \
            float h0 = __shfl_down(S[0], 1, 64);                           \
            float h1 = __shfl_down(S[1], 1, 64);                           \
            float h2 = __shfl_down(S[2], 1, 64);                           \
            float h3 = __shfl_down(S[3], 1, 64);                           \
            float h4 = __shfl_down(S[4], 1, 64);                           \
            float h5 = __shfl_down(S[5], 1, 64);                           \
            W[0] = ((S[0]+S[1]) + (S[2]+S[3])) + ((S[4]+S[5]) + S[6]);     \
            W[1] = W[0] + (S[7] - S[0]);                                   \
            W[2] = W[1] + (h0   - S[1]);                                   \
            W[3] = W[2] + (h1   - S[2]);                                   \
            W[4] = W[3] + (h2   - S[3]);                                   \
            W[5] = W[4] + (h3   - S[4]);                                   \
            W[6] = W[5] + (h4   - S[5]);                                   \
            W[7] = W[6] + (h5   - S[6]);                                   \
        }
        HWIN(sx,  Wx)
        HWIN(sy,  Wy)
        HWIN(s2,  W2)
        HWIN(sxy, Wxy)
#undef HWIN

        // ---- 4. retire oldest row (waits rx: vmcnt(4); W already extracted)
        {
            float x[8], y[8];
            unpack8(rxa, rxb, x); unpack8(rya, ryb, y);
#pragma unroll
            for (int q = 0; q < 8; ++q) {
                sx[q] -= x[q]; sy[q] -= y[q];
                s2[q]  = fmaf(-x[q], x[q], s2[q]);
                s2[q]  = fmaf(-y[q], y[q], s2[q]);
                sxy[q] = fmaf(-x[q], y[q], sxy[q]);
            }
        }
        // ---- 5. issue next retire-row loads (row r0+r+1, always in-bounds)
        {
            const int rr = (r0 + r + 1) * (IW / 4);
            rxa = X4[rr + c0]; rxb = X4[rr + c0 + 1];
            rya = Y4[rr + c0]; ryb = Y4[rr + c0 + 1];
        }
        __builtin_amdgcn_sched_barrier(0);   // pin issue point

        // ---- 6. SSIM at 8 output cols (pure VALU, shadows the loads) ----
#pragma unroll
        for (int m = 0; m < 8; ++m) {
            float Sv = ssim_raw(Wx[m], Wy[m], W2[m], Wxy[m]);
            accS += (8 * lane + m < OUTW) ? Sv : 0.0f;
        }
    }

    // block reduce -> one partial per block
#pragma unroll
    for (int o = 32; o > 0; o >>= 1)
        accS += __shfl_down(accS, o, 64);
    if (lane == 0) wsum[wv] = accS;
    __syncthreads();
    if (t == 0)
        partials[blockIdx.x] = (wsum[0] + wsum[1]) + (wsum[2] + wsum[3]);
}

__global__ __launch_bounds__(256) void ssim_finalize(const float* __restrict__ partials,
                                                     float* __restrict__ out) {
    __shared__ float wsum[4];
    const int t = threadIdx.x;
    float v = 0.0f;
    for (int i = t; i < NPART; i += 256) v += partials[i];
#pragma unroll
    for (int o = 32; o > 0; o >>= 1)
        v += __shfl_down(v, o, 64);
    if ((t & 63) == 0) wsum[t >> 6] = v;
    __syncthreads();
    if (t == 0)
        out[0] = 1.0f - ((wsum[0] + wsum[1]) + (wsum[2] + wsum[3])) / TOTAL_OUT;
}

extern "C" void kernel_launch(void* const* d_in, const int* in_sizes, int n_in,
                              void* d_out, int out_size, void* d_ws, size_t ws_size,
                              hipStream_t stream) {
    const float* X = (const float*)d_in[0];
    const float* Y = (const float*)d_in[1];
    float* partials = (float*)d_ws;          // NPART floats (4.4 KB)
    float* out = (float*)d_out;

    hipLaunchKernelGGL(ssim_main, dim3(NBLK), dim3(256), 0, stream,
                       X, Y, partials);
    hipLaunchKernelGGL(ssim_finalize, dim3(1), dim3(256), 0, stream,
                       partials, out);
}

// Round 4
// 292.304 us; speedup vs baseline: 1.0248x; 1.0248x over previous
//
#include <hip/hip_runtime.h>

// SSIM loss, fused. Round 10: r9 resubmit (infra failure last round).
//  - r8 POST-MORTEM: WRITE_SIZE=104 MB (scratch spill stores!) + VGPR=64.
//    __launch_bounds__(256,4) only sets MIN waves/EU; the backend targeted
//    8 waves/EU (64-VGPR budget) and honored the sched_barrier-pinned
//    prefetch by SPILLING it to scratch -> prefetch through HBM. Fix:
//    __launch_bounds__(256) + amdgpu_waves_per_eu(4,4) pins occupancy at
//    exactly 4 waves/EU -> 128-VGPR budget. Pipeline needs ~110 live.
//  - Schedule unchanged from r8: add(new, vmcnt(4)) -> issue next-new ->
//    sched_barrier -> shfl/W-chain -> subtract(retire, vmcnt(4)) -> issue
//    next-retire -> sched_barrier -> ssim x8. 8 loads in flight, each with
//    ~a full loop body of shadow.
//  - Structure: wave64 owns a 512-col x 11-row band; 8 cols/lane; 4 register
//    sum planes (Sx, Sy, Sxx+Syy, Sxy); horizontal halo = 6 shfl_down/plane;
//    no LDS, no barriers in hot loop.

#define IW    512
#define OUTW  506
#define BAND  11                 // output rows per wave; 46*11 = 506 exactly
#define NBANDS 46
#define NIMG  96
#define WPB   4                  // independent waves per block
#define NBLK  (NBANDS * NIMG / WPB)   // 1104 blocks
#define NPART NBLK
#define C1N2  0.2401f            // 1e-4 * 49^2
#define C2N2  2.1609f            // 9e-4 * 49^2
#define KA    (49.0f/24.0f)
#define KB    (49.0f/48.0f)
#define TOTAL_OUT 24579456.0f    // 96*506*506

__device__ __forceinline__ float ssim_raw(float Sx, float Sy, float S2, float Sxy) {
    float sxsy = Sx * Sy;
    float p    = fmaf(Sx, Sx, Sy * Sy);
    float a1   = fmaf(2.0f, sxsy, C1N2);
    float b1   = p + C1N2;
    float a2   = fmaf(KA, fmaf(49.0f, Sxy, -sxsy), C2N2);
    float b2   = fmaf(KB, fmaf(49.0f, S2, -p), C2N2);
    return (a1 * a2) * __builtin_amdgcn_rcpf(b1 * b2);
}

__device__ __forceinline__ void unpack8(float4 a, float4 b, float* d) {
    d[0]=a.x; d[1]=a.y; d[2]=a.z; d[3]=a.w;
    d[4]=b.x; d[5]=b.y; d[6]=b.z; d[7]=b.w;
}

__global__ __launch_bounds__(256)
__attribute__((amdgpu_waves_per_eu(4, 4)))
void ssim_main(const float* __restrict__ X,
               const float* __restrict__ Y,
               float* __restrict__ partials) {
    __shared__ float wsum[WPB];
    const int t    = threadIdx.x;
    const int wv   = t >> 6;
    const int lane = t & 63;
    const int gw   = blockIdx.x * WPB + wv;      // 0..4415
    const int img  = gw / NBANDS;
    const int band = gw - img * NBANDS;
    const int r0   = band * BAND;
    const float4* X4 = (const float4*)X + (size_t)img * (IW * IW / 4);
    const float4* Y4 = (const float4*)Y + (size_t)img * (IW * IW / 4);
    const int c0 = 2 * lane;                     // float4 index of col 8*lane

    // vertical sliding column sums, 8 cols/lane, 4 planes = 32 VGPR
    float sx[8], sy[8], s2[8], sxy[8];
#pragma unroll
    for (int q = 0; q < 8; ++q) { sx[q]=0.f; sy[q]=0.f; s2[q]=0.f; sxy[q]=0.f; }

    // prologue: rows r0 .. r0+5 (24 independent loads, one latency trip)
#pragma unroll
    for (int i = 0; i < 6; ++i) {
        const int ro = (r0 + i) * (IW / 4);
        float4 xa = X4[ro + c0], xb = X4[ro + c0 + 1];
        float4 ya = Y4[ro + c0], yb = Y4[ro + c0 + 1];
        float x[8], y[8];
        unpack8(xa, xb, x); unpack8(ya, yb, y);
#pragma unroll
        for (int q = 0; q < 8; ++q) {
            sx[q] += x[q]; sy[q] += y[q];
            s2[q]  = fmaf(x[q], x[q], s2[q]);
            s2[q]  = fmaf(y[q], y[q], s2[q]);
            sxy[q] = fmaf(x[q], y[q], sxy[q]);
        }
    }

    // prefetch for r=0: new row r0+6, retire row r0
    int rnaddr = (r0 + 6) * (IW / 4);
    float4 nxa = X4[rnaddr + c0], nxb = X4[rnaddr + c0 + 1];
    float4 nya = Y4[rnaddr + c0], nyb = Y4[rnaddr + c0 + 1];
    int rraddr = r0 * (IW / 4);
    float4 rxa = X4[rraddr + c0], rxb = X4[rraddr + c0 + 1];
    float4 rya = Y4[rraddr + c0], ryb = Y4[rraddr + c0 + 1];

    float accS = 0.0f;

#pragma unroll 1
    for (int r = 0; r < BAND; ++r) {
        // ---- 1. vertical add of prefetched new row (waits nx: vmcnt(4)) ----
        {
            float x[8], y[8];
            unpack8(nxa, nxb, x); unpack8(nya, nyb, y);
#pragma unroll
            for (int q = 0; q < 8; ++q) {
                sx[q] += x[q]; sy[q] += y[q];
                s2[q]  = fmaf(x[q], x[q], s2[q]);
                s2[q]  = fmaf(y[q], y[q], s2[q]);
                sxy[q] = fmaf(x[q], y[q], sxy[q]);
            }
        }
        // ---- 2. issue next new-row loads (regs just died; full-iter shadow)
        {
            const int rn = min(r0 + 7 + r, IW - 1) * (IW / 4);  // clamp: last iter value unused
            nxa = X4[rn + c0]; nxb = X4[rn + c0 + 1];
            nya = Y4[rn + c0]; nyb = Y4[rn + c0 + 1];
        }
        __builtin_amdgcn_sched_barrier(0);   // pin issue point: no sinking

        // ---- 3. horizontal 7-windows: halo = next lane's first 6 col sums
        float Wx[8], Wy[8], W2[8], Wxy[8];
#define HWIN(S, W)                                                         \
        {                                                                  \
            float h0 = __shfl_down(S[0], 1, 64);                           \
            float h1 = __shfl_down(S[1], 1, 64);                           \
            float h2 = __shfl_down(S[2], 1, 64);                           \
            float h3 = __shfl_down(S[3], 1, 64);                           \
            float h4 = __shfl_down(S[4], 1, 64);                           \
            float h5 = __shfl_down(S[5], 1, 64);                           \
            W[0] = ((S[0]+S[1]) + (S[2]+S[3])) + ((S[4]+S[5]) + S[6]);     \
            W[1] = W[0] + (S[7] - S[0]);                                   \
            W[2] = W[1] + (h0   - S[1]);                                   \
            W[3] = W[2] + (h1   - S[2]);                                   \
            W[4] = W[3] + (h2   - S[3]);                                   \
            W[5] = W[4] + (h3   - S[4]);                                   \
            W[6] = W[5] + (h4   - S[5]);                                   \
            W[7] = W[6] + (h5   - S[6]);                                   \
        }
        HWIN(sx,  Wx)
        HWIN(sy,  Wy)
        HWIN(s2,  W2)
        HWIN(sxy, Wxy)
#undef HWIN

        // ---- 4. retire oldest row (waits rx: vmcnt(4); W already extracted)
        {
            float x[8], y[8];
            unpack8(rxa, rxb, x); unpack8(rya, ryb, y);
#pragma unroll
            for (int q = 0; q < 8; ++q) {
                sx[q] -= x[q]; sy[q] -= y[q];
                s2[q]  = fmaf(-x[q], x[q], s2[q]);
                s2[q]  = fmaf(-y[q], y[q], s2[q]);
                sxy[q] = fmaf(-x[q], y[q], sxy[q]);
            }
        }
        // ---- 5. issue next retire-row loads (row r0+r+1, always in-bounds)
        {
            const int rr = (r0 + r + 1) * (IW / 4);
            rxa = X4[rr + c0]; rxb = X4[rr + c0 + 1];
            rya = Y4[rr + c0]; ryb = Y4[rr + c0 + 1];
        }
        __builtin_amdgcn_sched_barrier(0);   // pin issue point

        // ---- 6. SSIM at 8 output cols (pure VALU, shadows the loads) ----
#pragma unroll
        for (int m = 0; m < 8; ++m) {
            float Sv = ssim_raw(Wx[m], Wy[m], W2[m], Wxy[m]);
            accS += (8 * lane + m < OUTW) ? Sv : 0.0f;
        }
    }

    // block reduce -> one partial per block
#pragma unroll
    for (int o = 32; o > 0; o >>= 1)
        accS += __shfl_down(accS, o, 64);
    if (lane == 0) wsum[wv] = accS;
    __syncthreads();
    if (t == 0)
        partials[blockIdx.x] = (wsum[0] + wsum[1]) + (wsum[2] + wsum[3]);
}

__global__ __launch_bounds__(256) void ssim_finalize(const float* __restrict__ partials,
                                                     float* __restrict__ out) {
    __shared__ float wsum[4];
    const int t = threadIdx.x;
    float v = 0.0f;
    for (int i = t; i < NPART; i += 256) v += partials[i];
#pragma unroll
    for (int o = 32; o > 0; o >>= 1)
        v += __shfl_down(v, o, 64);
    if ((t & 63) == 0) wsum[t >> 6] = v;
    __syncthreads();
    if (t == 0)
        out[0] = 1.0f - ((wsum[0] + wsum[1]) + (wsum[2] + wsum[3])) / TOTAL_OUT;
}

extern "C" void kernel_launch(void* const* d_in, const int* in_sizes, int n_in,
                              void* d_out, int out_size, void* d_ws, size_t ws_size,
                              hipStream_t stream) {
    const float* X = (const float*)d_in[0];
    const float* Y = (const float*)d_in[1];
    float* partials = (float*)d_ws;          // NPART floats (4.4 KB)
    float* out = (float*)d_out;

    hipLaunchKernelGGL(ssim_main, dim3(NBLK), dim3(256), 0, stream,
                       X, Y, partials);
    hipLaunchKernelGGL(ssim_finalize, dim3(1), dim3(256), 0, stream,
                       partials, out);
}

// Round 5
// 241.409 us; speedup vs baseline: 1.2408x; 1.2108x over previous
//
#include <hip/hip_runtime.h>

// SSIM loss, fused. Round 11: compact wave-autonomous bands, TLP does the hiding.
//  - r8/r10 POST-MORTEM: backend pins the 64-VGPR / 8-waves-per-EU budget no
//    matter what (launch_bounds min arg and amdgpu_waves_per_eu both failed to
//    raise it); any schedule needing >64 live regs = scratch spill traffic
//    (WRITE_SIZE 101 MB). STOP forcing a register pipeline.
//  - NEW THEORY: whole input (201 MB) fits in 256 MB L3 -> retire/halo
//    re-reads are L3 hits, nearly free at HBM. The real constraint is
//    latency hiding = resident waves. r7 (56 VGPR, loads sunk to use) was
//    wave-starved: 4.3 offered waves/SIMD. Fix: BAND 11 -> 6, 85 bands x 96
//    imgs = 8160 waves = 8.0 offered/SIMD. Keep the compact codegen shape
//    the compiler handles without spills: no prefetch regs, no
//    sched_barrier, loads adjacent to their use.
//  - Per iter: load+add new row (r+6) -> HWIN (shfl halo) + ssim x8 ->
//    load+subtract retire row (r). Peak live ~55 regs < 64 budget.
//  - Last band (r0=504) early-exits after 2 rows (wave-uniform break);
//    all its loads stay in-bounds (max row touched = 511).

#define IW    512
#define OUTW  506
#define BAND  6                  // output rows per wave
#define NBANDS 85                // ceil(506/6); last band does 2 rows
#define NIMG  96
#define WPB   4                  // waves per block
#define NBLK  (NBANDS * NIMG / WPB)   // 2040 blocks
#define NPART NBLK
#define C1N2  0.2401f            // 1e-4 * 49^2
#define C2N2  2.1609f            // 9e-4 * 49^2
#define KA    (49.0f/24.0f)
#define KB    (49.0f/48.0f)
#define TOTAL_OUT 24579456.0f    // 96*506*506

__device__ __forceinline__ float ssim_raw(float Sx, float Sy, float S2, float Sxy) {
    float sxsy = Sx * Sy;
    float p    = fmaf(Sx, Sx, Sy * Sy);
    float a1   = fmaf(2.0f, sxsy, C1N2);
    float b1   = p + C1N2;
    float a2   = fmaf(KA, fmaf(49.0f, Sxy, -sxsy), C2N2);
    float b2   = fmaf(KB, fmaf(49.0f, S2, -p), C2N2);
    return (a1 * a2) * __builtin_amdgcn_rcpf(b1 * b2);
}

__device__ __forceinline__ void unpack8(float4 a, float4 b, float* d) {
    d[0]=a.x; d[1]=a.y; d[2]=a.z; d[3]=a.w;
    d[4]=b.x; d[5]=b.y; d[6]=b.z; d[7]=b.w;
}

__global__ __launch_bounds__(256)
void ssim_main(const float* __restrict__ X,
               const float* __restrict__ Y,
               float* __restrict__ partials) {
    __shared__ float wsum[WPB];
    const int t    = threadIdx.x;
    const int wv   = t >> 6;
    const int lane = t & 63;
    const int gw   = blockIdx.x * WPB + wv;      // 0..8159
    const int img  = gw / NBANDS;
    const int band = gw - img * NBANDS;
    const int r0   = band * BAND;
    const float4* X4 = (const float4*)X + (size_t)img * (IW * IW / 4);
    const float4* Y4 = (const float4*)Y + (size_t)img * (IW * IW / 4);
    const int c0 = 2 * lane;                     // float4 index of col 8*lane

    // vertical sliding column sums, 8 cols/lane, 4 planes = 32 VGPR
    float sx[8], sy[8], s2[8], sxy[8];
#pragma unroll
    for (int q = 0; q < 8; ++q) { sx[q]=0.f; sy[q]=0.f; s2[q]=0.f; sxy[q]=0.f; }

    // prologue: rows r0 .. r0+5
#pragma unroll
    for (int i = 0; i < 6; ++i) {
        const int ro = (r0 + i) * (IW / 4);
        float4 xa = X4[ro + c0], xb = X4[ro + c0 + 1];
        float4 ya = Y4[ro + c0], yb = Y4[ro + c0 + 1];
        float x[8], y[8];
        unpack8(xa, xb, x); unpack8(ya, yb, y);
#pragma unroll
        for (int q = 0; q < 8; ++q) {
            sx[q] += x[q]; sy[q] += y[q];
            s2[q]  = fmaf(x[q], x[q], s2[q]);
            s2[q]  = fmaf(y[q], y[q], s2[q]);
            sxy[q] = fmaf(x[q], y[q], sxy[q]);
        }
    }

    float accS = 0.0f;

#pragma unroll 1
    for (int r = 0; r < BAND; ++r) {
        const int orow = r0 + r;
        if (orow >= OUTW) break;                 // wave-uniform (last band)

        // ---- add new input row (orow+6): window rows [orow .. orow+6] ----
        {
            const int rn = (orow + 6) * (IW / 4);
            float4 xa = X4[rn + c0], xb = X4[rn + c0 + 1];
            float4 ya = Y4[rn + c0], yb = Y4[rn + c0 + 1];
            float x[8], y[8];
            unpack8(xa, xb, x); unpack8(ya, yb, y);
#pragma unroll
            for (int q = 0; q < 8; ++q) {
                sx[q] += x[q]; sy[q] += y[q];
                s2[q]  = fmaf(x[q], x[q], s2[q]);
                s2[q]  = fmaf(y[q], y[q], s2[q]);
                sxy[q] = fmaf(x[q], y[q], sxy[q]);
            }
        }

        // ---- horizontal 7-windows: halo = next lane's first 6 col sums ----
        float Wx[8], Wy[8], W2[8], Wxy[8];
#define HWIN(S, W)                                                         \
        {                                                                  \
            float h0 = __shfl_down(S[0], 1, 64);                           \
            float h1 = __shfl_down(S[1], 1, 64);                           \
            float h2 = __shfl_down(S[2], 1, 64);                           \
            float h3 = __shfl_down(S[3], 1, 64);                           \
            float h4 = __shfl_down(S[4], 1, 64);                           \
            float h5 = __shfl_down(S[5], 1, 64);                           \
            W[0] = ((S[0]+S[1]) + (S[2]+S[3])) + ((S[4]+S[5]) + S[6]);     \
            W[1] = W[0] + (S[7] - S[0]);                                   \
            W[2] = W[1] + (h0   - S[1]);                                   \
            W[3] = W[2] + (h1   - S[2]);                                   \
            W[4] = W[3] + (h2   - S[3]);                                   \
            W[5] = W[4] + (h3   - S[4]);                                   \
            W[6] = W[5] + (h4   - S[5]);                                   \
            W[7] = W[6] + (h5   - S[6]);                                   \
        }
        HWIN(sx,  Wx)
        HWIN(sy,  Wy)
        HWIN(s2,  W2)
        HWIN(sxy, Wxy)
#undef HWIN

        // ---- SSIM at 8 output cols ----
#pragma unroll
        for (int m = 0; m < 8; ++m) {
            float Sv = ssim_raw(Wx[m], Wy[m], W2[m], Wxy[m]);
            accS += (8 * lane + m < OUTW) ? Sv : 0.0f;
        }

        // ---- retire oldest row (orow): L3-hit re-read, sunk to use ----
        {
            const int rr = orow * (IW / 4);
            float4 xa = X4[rr + c0], xb = X4[rr + c0 + 1];
            float4 ya = Y4[rr + c0], yb = Y4[rr + c0 + 1];
            float x[8], y[8];
            unpack8(xa, xb, x); unpack8(ya, yb, y);
#pragma unroll
            for (int q = 0; q < 8; ++q) {
                sx[q] -= x[q]; sy[q] -= y[q];
                s2[q]  = fmaf(-x[q], x[q], s2[q]);
                s2[q]  = fmaf(-y[q], y[q], s2[q]);
                sxy[q] = fmaf(-x[q], y[q], sxy[q]);
            }
        }
    }

    // block reduce -> one partial per block
#pragma unroll
    for (int o = 32; o > 0; o >>= 1)
        accS += __shfl_down(accS, o, 64);
    if (lane == 0) wsum[wv] = accS;
    __syncthreads();
    if (t == 0)
        partials[blockIdx.x] = (wsum[0] + wsum[1]) + (wsum[2] + wsum[3]);
}

__global__ __launch_bounds__(256) void ssim_finalize(const float* __restrict__ partials,
                                                     float* __restrict__ out) {
    __shared__ float wsum[4];
    const int t = threadIdx.x;
    float v = 0.0f;
    for (int i = t; i < NPART; i += 256) v += partials[i];
#pragma unroll
    for (int o = 32; o > 0; o >>= 1)
        v += __shfl_down(v, o, 64);
    if ((t & 63) == 0) wsum[t >> 6] = v;
    __syncthreads();
    if (t == 0)
        out[0] = 1.0f - ((wsum[0] + wsum[1]) + (wsum[2] + wsum[3])) / TOTAL_OUT;
}

extern "C" void kernel_launch(void* const* d_in, const int* in_sizes, int n_in,
                              void* d_out, int out_size, void* d_ws, size_t ws_size,
                              hipStream_t stream) {
    const float* X = (const float*)d_in[0];
    const float* Y = (const float*)d_in[1];
    float* partials = (float*)d_ws;          // NPART floats (8.2 KB)
    float* out = (float*)d_out;

    hipLaunchKernelGGL(ssim_main, dim3(NBLK), dim3(256), 0, stream,
                       X, Y, partials);
    hipLaunchKernelGGL(ssim_finalize, dim3(1), dim3(256), 0, stream,
                       partials, out);
}

// Round 7
// 235.034 us; speedup vs baseline: 1.2745x; 1.0271x over previous
//
#include <hip/hip_runtime.h>

// SSIM loss, fused. Round 13: r12 resubmit (broker/container infra failure
// last round — same error signature as round 3, which succeeded on resubmit).
//  - r11 POST-MORTEM: clean codegen (48 VGPR, no spills) but VALUBusy 24% —
//    two serialized sunk-to-use global waits per iter (~600-900cy each) and
//    TLP (~4 waves/SIMD effective) can't cover them. Register prefetch is
//    impossible under the 64-VGPR wall (r8/r10: spills). The zero-VGPR
//    prefetch mechanism is global_load_lds async DMA.
//  - Each wave stages next-new-row (X+Y, 4 KB) into its private LDS ring
//    slot one iteration ahead; consume via ds_read_b128 (~120cy). Explicit
//    s_waitcnt vmcnt(0) before consume drains only the iteration-old DMA.
//    Retire row stays a sunk global load (7-iters-ago address, ~L2).
//  - LDS ring[4 waves][2 slots][1024 floats] = 32768 B -> 5 blocks/CU
//    (20 waves/CU). wsum aliases the ring after a tail barrier (stage
//    guards ensure zero outstanding DMAs at loop exit).

#define IW    512
#define OUTW  506
#define BAND  6                  // output rows per wave
#define NBANDS 85                // ceil(506/6); last band does 2 rows
#define NIMG  96
#define WPB   4                  // waves per block
#define NBLK  (NBANDS * NIMG / WPB)   // 2040 blocks
#define NPART NBLK
#define C1N2  0.2401f            // 1e-4 * 49^2
#define C2N2  2.1609f            // 9e-4 * 49^2
#define KA    (49.0f/24.0f)
#define KB    (49.0f/48.0f)
#define TOTAL_OUT 24579456.0f    // 96*506*506

typedef const __attribute__((address_space(1))) unsigned int* gas1_t;
typedef __attribute__((address_space(3))) unsigned int* las3_t;

// Stage one 2 KB row (512 floats) into LDS: 2 DMA instrs, 1 KB each.
// HW semantics: per-lane GLOBAL src address; LDS dest = uniform base + 16*lane.
__device__ __forceinline__ void stage_row(const float* g, float* l, int lane) {
    __builtin_amdgcn_global_load_lds((gas1_t)(g + 4 * lane),       (las3_t)l,         16, 0, 0);
    __builtin_amdgcn_global_load_lds((gas1_t)(g + 256 + 4 * lane), (las3_t)(l + 256), 16, 0, 0);
}

__device__ __forceinline__ float ssim_raw(float Sx, float Sy, float S2, float Sxy) {
    float sxsy = Sx * Sy;
    float p    = fmaf(Sx, Sx, Sy * Sy);
    float a1   = fmaf(2.0f, sxsy, C1N2);
    float b1   = p + C1N2;
    float a2   = fmaf(KA, fmaf(49.0f, Sxy, -sxsy), C2N2);
    float b2   = fmaf(KB, fmaf(49.0f, S2, -p), C2N2);
    return (a1 * a2) * __builtin_amdgcn_rcpf(b1 * b2);
}

__device__ __forceinline__ void unpack8(float4 a, float4 b, float* d) {
    d[0]=a.x; d[1]=a.y; d[2]=a.z; d[3]=a.w;
    d[4]=b.x; d[5]=b.y; d[6]=b.z; d[7]=b.w;
}

__global__ __launch_bounds__(256)
void ssim_main(const float* __restrict__ X,
               const float* __restrict__ Y,
               float* __restrict__ partials) {
    // ring[wave][slot][0..511]=X row, [512..1023]=Y row. 32768 B exactly.
    __shared__ float ring[WPB][2][1024];

    const int t    = threadIdx.x;
    const int wv   = t >> 6;
    const int lane = t & 63;
    const int gw   = blockIdx.x * WPB + wv;      // 0..8159
    const int img  = gw / NBANDS;
    const int band = gw - img * NBANDS;
    const int r0   = band * BAND;
    const float* Xf = X + (size_t)img * IW * IW;
    const float* Yf = Y + (size_t)img * IW * IW;
    const float4* X4 = (const float4*)Xf;
    const float4* Y4 = (const float4*)Yf;
    const int c0 = 2 * lane;                     // float4 index of col 8*lane

    // Kick off DMA for rows r0+6 (slot 0) and r0+7 (slot 1): they fly
    // across the whole 6-row prologue.
    stage_row(Xf + (size_t)(r0 + 6) * IW, &ring[wv][0][0],   lane);
    stage_row(Yf + (size_t)(r0 + 6) * IW, &ring[wv][0][512], lane);
    stage_row(Xf + (size_t)(r0 + 7) * IW, &ring[wv][1][0],   lane);
    stage_row(Yf + (size_t)(r0 + 7) * IW, &ring[wv][1][512], lane);

    // vertical sliding column sums, 8 cols/lane, 4 planes = 32 VGPR
    float sx[8], sy[8], s2[8], sxy[8];
#pragma unroll
    for (int q = 0; q < 8; ++q) { sx[q]=0.f; sy[q]=0.f; s2[q]=0.f; sxy[q]=0.f; }

    // prologue: rows r0 .. r0+5 via direct global loads (24 indep loads)
#pragma unroll
    for (int i = 0; i < 6; ++i) {
        const int ro = (r0 + i) * (IW / 4);
        float4 xa = X4[ro + c0], xb = X4[ro + c0 + 1];
        float4 ya = Y4[ro + c0], yb = Y4[ro + c0 + 1];
        float x[8], y[8];
        unpack8(xa, xb, x); unpack8(ya, yb, y);
#pragma unroll
        for (int q = 0; q < 8; ++q) {
            sx[q] += x[q]; sy[q] += y[q];
            s2[q]  = fmaf(x[q], x[q], s2[q]);
            s2[q]  = fmaf(y[q], y[q], s2[q]);
            sxy[q] = fmaf(x[q], y[q], sxy[q]);
        }
    }

    float accS = 0.0f;

#pragma unroll 1
    for (int r = 0; r < BAND; ++r) {
        const int orow = r0 + r;
        if (orow >= OUTW) break;                 // wave-uniform (last band)
        const int p = r & 1;

        // ---- consume staged new row (orow+6) from LDS ----
        // Drain DMAs: the slot-p stage is >=1 full iteration old.
        asm volatile("s_waitcnt vmcnt(0)" ::: "memory");
        {
            const float* sl = &ring[wv][p][0];
            float4 xa = *(const float4*)(sl + 8 * lane);
            float4 xb = *(const float4*)(sl + 8 * lane + 4);
            float4 ya = *(const float4*)(sl + 512 + 8 * lane);
            float4 yb = *(const float4*)(sl + 512 + 8 * lane + 4);
            float x[8], y[8];
            unpack8(xa, xb, x); unpack8(ya, yb, y);
#pragma unroll
            for (int q = 0; q < 8; ++q) {
                sx[q] += x[q]; sy[q] += y[q];
                s2[q]  = fmaf(x[q], x[q], s2[q]);
                s2[q]  = fmaf(y[q], y[q], s2[q]);
                sxy[q] = fmaf(x[q], y[q], sxy[q]);
            }
        }

        // ---- issue DMA for row orow+8 into slot p (consumed at r+2) ----
        // Guard: only if it will actually be consumed -> zero outstanding
        // DMAs at loop exit (wsum aliasing below is safe).
        if (r + 2 < BAND && orow + 2 < OUTW) {
            stage_row(Xf + (size_t)(orow + 8) * IW, &ring[wv][p][0],   lane);
            stage_row(Yf + (size_t)(orow + 8) * IW, &ring[wv][p][512], lane);
        }

        // ---- horizontal 7-windows: halo = next lane's first 6 col sums ----
        float Wx[8], Wy[8], W2[8], Wxy[8];
#define HWIN(S, W)                                                         \
        {                                                                  \
            float h0 = __shfl_down(S[0], 1, 64);                           \
            float h1 = __shfl_down(S[1], 1, 64);                           \
            float h2 = __shfl_down(S[2], 1, 64);                           \
            float h3 = __shfl_down(S[3], 1, 64);                           \
            float h4 = __shfl_down(S[4], 1, 64);                           \
            float h5 = __shfl_down(S[5], 1, 64);                           \
            W[0] = ((S[0]+S[1]) + (S[2]+S[3])) + ((S[4]+S[5]) + S[6]);     \
            W[1] = W[0] + (S[7] - S[0]);                                   \
            W[2] = W[1] + (h0   - S[1]);                                   \
            W[3] = W[2] + (h1   - S[2]);                                   \
            W[4] = W[3] + (h2   - S[3]);                                   \
            W[5] = W[4] + (h3   - S[4]);                                   \
            W[6] = W[5] + (h4   - S[5]);                                   \
            W[7] = W[6] + (h5   - S[6]);                                   \
        }
        HWIN(sx,  Wx)
        HWIN(sy,  Wy)
        HWIN(s2,  W2)
        HWIN(sxy, Wxy)
#undef HWIN

        // ---- SSIM at 8 output cols ----
#pragma unroll
        for (int m = 0; m < 8; ++m) {
            float Sv = ssim_raw(Wx[m], Wy[m], W2[m], Wxy[m]);
            accS += (8 * lane + m < OUTW) ? Sv : 0.0f;
        }

        // ---- retire oldest row (orow): sunk global re-read (~L2) ----
        {
            const int rr = orow * (IW / 4);
            float4 xa = X4[rr + c0], xb = X4[rr + c0 + 1];
            float4 ya = Y4[rr + c0], yb = Y4[rr + c0 + 1];
            float x[8], y[8];
            unpack8(xa, xb, x); unpack8(ya, yb, y);
#pragma unroll
            for (int q = 0; q < 8; ++q) {
                sx[q] -= x[q]; sy[q] -= y[q];
                s2[q]  = fmaf(-x[q], x[q], s2[q]);
                s2[q]  = fmaf(-y[q], y[q], s2[q]);
                sxy[q] = fmaf(-x[q], y[q], sxy[q]);
            }
        }
    }

    // block reduce -> one partial per block. wsum aliases the ring (all
    // DMAs drained: stage guards + per-iter vmcnt(0); barrier quiesces ring).
#pragma unroll
    for (int o = 32; o > 0; o >>= 1)
        accS += __shfl_down(accS, o, 64);
    __syncthreads();                      // ring no longer in use by any wave
    float* wsum = &ring[0][0][0];
    if (lane == 0) wsum[wv] = accS;
    __syncthreads();
    if (t == 0)
        partials[blockIdx.x] = (wsum[0] + wsum[1]) + (wsum[2] + wsum[3]);
}

__global__ __launch_bounds__(256) void ssim_finalize(const float* __restrict__ partials,
                                                     float* __restrict__ out) {
    __shared__ float wsum[4];
    const int t = threadIdx.x;
    float v = 0.0f;
    for (int i = t; i < NPART; i += 256) v += partials[i];
#pragma unroll
    for (int o = 32; o > 0; o >>= 1)
        v += __shfl_down(v, o, 64);
    if ((t & 63) == 0) wsum[t >> 6] = v;
    __syncthreads();
    if (t == 0)
        out[0] = 1.0f - ((wsum[0] + wsum[1]) + (wsum[2] + wsum[3])) / TOTAL_OUT;
}

extern "C" void kernel_launch(void* const* d_in, const int* in_sizes, int n_in,
                              void* d_out, int out_size, void* d_ws, size_t ws_size,
                              hipStream_t stream) {
    const float* X = (const float*)d_in[0];
    const float* Y = (const float*)d_in[1];
    float* partials = (float*)d_ws;          // NPART floats (8.2 KB)
    float* out = (float*)d_out;

    hipLaunchKernelGGL(ssim_main, dim3(NBLK), dim3(256), 0, stream,
                       X, Y, partials);
    hipLaunchKernelGGL(ssim_finalize, dim3(1), dim3(256), 0, stream,
                       partials, out);
}

// Round 8
// 231.571 us; speedup vs baseline: 1.2936x; 1.0150x over previous
//
#include <hip/hip_runtime.h>

// SSIM loss, fused. Round 14: r13 + counted-vmcnt discipline (T3/T4).
//  - r13 POST-MORTEM: staging worked but the schedule drained it. Stages
//    were issued mid-iteration; the end-of-iter retire wait is necessarily
//    vmcnt(0) (retire loads are newest; vmcnt retires oldest-first) -> it
//    drained the fresh DMAs with only ~600cy shadow (~1000+cy exposed), and
//    my consume wait was a literal vmcnt(0) re-drain. ~5000cy/iter wall vs
//    ~500cy VALU -> VALUBusy 26%.
//  - FIX: stage DMAs at the END of the iteration, after the subtract's
//    vmcnt(0) (pinned below it by sched_barrier). Invariant: at consume,
//    outstanding = exactly the 4 DMAs staged last iteration (for the NEXT
//    consume); the needed slot was drained by the previous retire wait.
//    Consume = inline-asm {s_waitcnt vmcnt(4); ds_read_b128 x4;
//    s_waitcnt lgkmcnt(0)} so the compiler cannot insert its own
//    conservative vmcnt(0) before the LDS reads (LDS-DMA aliasing).
//  - Exposed stall/iter drops to ~retire-L2 (~300cy), inside one wait.
//  - Structure unchanged: BAND=6, WPB=4, 2-slot wave-private ring (32 KB),
//    8 cols/lane, 4 register sum planes, shfl halo, no hot-loop barriers.

#define IW    512
#define OUTW  506
#define BAND  6                  // output rows per wave
#define NBANDS 85                // ceil(506/6); last band does 2 rows
#define NIMG  96
#define WPB   4                  // waves per block
#define NBLK  (NBANDS * NIMG / WPB)   // 2040 blocks
#define NPART NBLK
#define C1N2  0.2401f            // 1e-4 * 49^2
#define C2N2  2.1609f            // 9e-4 * 49^2
#define KA    (49.0f/24.0f)
#define KB    (49.0f/48.0f)
#define TOTAL_OUT 24579456.0f    // 96*506*506

typedef const __attribute__((address_space(1))) unsigned int* gas1_t;
typedef __attribute__((address_space(3))) unsigned int* las3_t;
typedef float v4f __attribute__((ext_vector_type(4)));

// Stage one 2 KB row (512 floats) into LDS: 2 DMA instrs, 1 KB each.
// HW: per-lane GLOBAL src address; LDS dest = uniform base + 16*lane.
__device__ __forceinline__ void stage_row(const float* g, float* l, int lane) {
    __builtin_amdgcn_global_load_lds((gas1_t)(g + 4 * lane),       (las3_t)l,         16, 0, 0);
    __builtin_amdgcn_global_load_lds((gas1_t)(g + 256 + 4 * lane), (las3_t)(l + 256), 16, 0, 0);
}

__device__ __forceinline__ float ssim_raw(float Sx, float Sy, float S2, float Sxy) {
    float sxsy = Sx * Sy;
    float p    = fmaf(Sx, Sx, Sy * Sy);
    float a1   = fmaf(2.0f, sxsy, C1N2);
    float b1   = p + C1N2;
    float a2   = fmaf(KA, fmaf(49.0f, Sxy, -sxsy), C2N2);
    float b2   = fmaf(KB, fmaf(49.0f, S2, -p), C2N2);
    return (a1 * a2) * __builtin_amdgcn_rcpf(b1 * b2);
}

__device__ __forceinline__ void unpack8(float4 a, float4 b, float* d) {
    d[0]=a.x; d[1]=a.y; d[2]=a.z; d[3]=a.w;
    d[4]=b.x; d[5]=b.y; d[6]=b.z; d[7]=b.w;
}

__device__ __forceinline__ void unpack8v(v4f a, v4f b, float* d) {
    d[0]=a.x; d[1]=a.y; d[2]=a.z; d[3]=a.w;
    d[4]=b.x; d[5]=b.y; d[6]=b.z; d[7]=b.w;
}

__global__ __launch_bounds__(256)
void ssim_main(const float* __restrict__ X,
               const float* __restrict__ Y,
               float* __restrict__ partials) {
    // ring[wave][slot][0..511]=X row, [512..1023]=Y row. 32768 B exactly.
    __shared__ float ring[WPB][2][1024];

    const int t    = threadIdx.x;
    const int wv   = t >> 6;
    const int lane = t & 63;
    const int gw   = blockIdx.x * WPB + wv;      // 0..8159
    const int img  = gw / NBANDS;
    const int band = gw - img * NBANDS;
    const int r0   = band * BAND;
    const float* Xf = X + (size_t)img * IW * IW;
    const float* Yf = Y + (size_t)img * IW * IW;
    const float4* X4 = (const float4*)Xf;
    const float4* Y4 = (const float4*)Yf;
    const int c0 = 2 * lane;                     // float4 index of col 8*lane

    // Kick off DMA for rows r0+6 (slot 0) and r0+7 (slot 1): they complete
    // under the 6-row prologue (whose load waits drain them progressively).
    stage_row(Xf + (size_t)(r0 + 6) * IW, &ring[wv][0][0],   lane);
    stage_row(Yf + (size_t)(r0 + 6) * IW, &ring[wv][0][512], lane);
    stage_row(Xf + (size_t)(r0 + 7) * IW, &ring[wv][1][0],   lane);
    stage_row(Yf + (size_t)(r0 + 7) * IW, &ring[wv][1][512], lane);

    // vertical sliding column sums, 8 cols/lane, 4 planes = 32 VGPR
    float sx[8], sy[8], s2[8], sxy[8];
#pragma unroll
    for (int q = 0; q < 8; ++q) { sx[q]=0.f; sy[q]=0.f; s2[q]=0.f; sxy[q]=0.f; }

    // prologue: rows r0 .. r0+5 via direct global loads (24 indep loads)
#pragma unroll
    for (int i = 0; i < 6; ++i) {
        const int ro = (r0 + i) * (IW / 4);
        float4 xa = X4[ro + c0], xb = X4[ro + c0 + 1];
        float4 ya = Y4[ro + c0], yb = Y4[ro + c0 + 1];
        float x[8], y[8];
        unpack8(xa, xb, x); unpack8(ya, yb, y);
#pragma unroll
        for (int q = 0; q < 8; ++q) {
            sx[q] += x[q]; sy[q] += y[q];
            s2[q]  = fmaf(x[q], x[q], s2[q]);
            s2[q]  = fmaf(y[q], y[q], s2[q]);
            sxy[q] = fmaf(x[q], y[q], sxy[q]);
        }
    }

    float accS = 0.0f;

#pragma unroll 1
    for (int r = 0; r < BAND; ++r) {
        const int orow = r0 + r;
        if (orow >= OUTW) break;                 // wave-uniform (last band)
        const int p = r & 1;

        // ---- consume staged new row (orow+6) from LDS ----
        // Counted wait: outstanding = at most the 4 DMAs staged last iter
        // (they feed the NEXT consume). The slot-p DMAs are >=2 iterations
        // old and were drained by the previous retire wait. Bundled asm so
        // the compiler cannot insert a conservative vmcnt(0) of its own.
        {
            const unsigned a0 =
                (unsigned)(size_t)(las3_t)&ring[wv][p][0] + 32u * (unsigned)lane;
            v4f xa, xb, ya, yb;
            asm volatile(
                "s_waitcnt vmcnt(4)\n\t"
                "ds_read_b128 %0, %4\n\t"
                "ds_read_b128 %1, %4 offset:16\n\t"
                "ds_read_b128 %2, %4 offset:2048\n\t"
                "ds_read_b128 %3, %4 offset:2064\n\t"
                "s_waitcnt lgkmcnt(0)"
                : "=&v"(xa), "=&v"(xb), "=&v"(ya), "=&v"(yb)
                : "v"(a0)
                : "memory");
            float x[8], y[8];
            unpack8v(xa, xb, x); unpack8v(ya, yb, y);
#pragma unroll
            for (int q = 0; q < 8; ++q) {
                sx[q] += x[q]; sy[q] += y[q];
                s2[q]  = fmaf(x[q], x[q], s2[q]);
                s2[q]  = fmaf(y[q], y[q], s2[q]);
                sxy[q] = fmaf(x[q], y[q], sxy[q]);
            }
        }

        // ---- horizontal 7-windows: halo = next lane's first 6 col sums ----
        float Wx[8], Wy[8], W2[8], Wxy[8];
#define HWIN(S, W)                                                         \
        {                                                                  \
            float h0 = __shfl_down(S[0], 1, 64);                           \
            float h1 = __shfl_down(S[1], 1, 64);                           \
            float h2 = __shfl_down(S[2], 1, 64);                           \
            float h3 = __shfl_down(S[3], 1, 64);                           \
            float h4 = __shfl_down(S[4], 1, 64);                           \
            float h5 = __shfl_down(S[5], 1, 64);                           \
            W[0] = ((S[0]+S[1]) + (S[2]+S[3])) + ((S[4]+S[5]) + S[6]);     \
            W[1] = W[0] + (S[7] - S[0]);                                   \
            W[2] = W[1] + (h0   - S[1]);                                   \
            W[3] = W[2] + (h1   - S[2]);                                   \
            W[4] = W[3] + (h2   - S[3]);                                   \
            W[5] = W[4] + (h3   - S[4]);                                   \
            W[6] = W[5] + (h4   - S[5]);                                   \
            W[7] = W[6] + (h5   - S[6]);                                   \
        }
        HWIN(sx,  Wx)
        HWIN(sy,  Wy)
        HWIN(s2,  W2)
        HWIN(sxy, Wxy)
#undef HWIN

        // ---- SSIM at 8 output cols ----
#pragma unroll
        for (int m = 0; m < 8; ++m) {
            float Sv = ssim_raw(Wx[m], Wy[m], W2[m], Wxy[m]);
            accS += (8 * lane + m < OUTW) ? Sv : 0.0f;
        }

        // ---- retire oldest row (orow): sunk global re-read (~L2) ----
        // Retire loads are the NEWEST vmem here -> the compiler's wait is
        // vmcnt(0), which also drains last iteration's DMAs (full-iteration
        // shadow). One overlapped wait; deterministic vmcnt=0 afterwards.
        {
            const int rr = orow * (IW / 4);
            float4 xa = X4[rr + c0], xb = X4[rr + c0 + 1];
            float4 ya = Y4[rr + c0], yb = Y4[rr + c0 + 1];
            float x[8], y[8];
            unpack8(xa, xb, x); unpack8(ya, yb, y);
#pragma unroll
            for (int q = 0; q < 8; ++q) {
                sx[q] -= x[q]; sy[q] -= y[q];
                s2[q]  = fmaf(-x[q], x[q], s2[q]);
                s2[q]  = fmaf(-y[q], y[q], s2[q]);
                sxy[q] = fmaf(-x[q], y[q], sxy[q]);
            }
        }

        // ---- stage row orow+8 into slot p for r+2 — AFTER the retire
        // wait (pinned by sched_barrier): gets a full-iteration+ shadow.
        __builtin_amdgcn_sched_barrier(0);
        if (r + 2 < BAND && orow + 2 < OUTW) {
            stage_row(Xf + (size_t)(orow + 8) * IW, &ring[wv][p][0],   lane);
            stage_row(Yf + (size_t)(orow + 8) * IW, &ring[wv][p][512], lane);
        }
    }

    // block reduce -> one partial per block. wsum aliases the ring (stage
    // guards ensure every DMA was consumed -> vmcnt drained before exit).
#pragma unroll
    for (int o = 32; o > 0; o >>= 1)
        accS += __shfl_down(accS, o, 64);
    __syncthreads();                      // ring no longer in use by any wave
    float* wsum = &ring[0][0][0];
    if (lane == 0) wsum[wv] = accS;
    __syncthreads();
    if (t == 0)
        partials[blockIdx.x] = (wsum[0] + wsum[1]) + (wsum[2] + wsum[3]);
}

__global__ __launch_bounds__(256) void ssim_finalize(const float* __restrict__ partials,
                                                     float* __restrict__ out) {
    __shared__ float wsum[4];
    const int t = threadIdx.x;
    float v = 0.0f;
    for (int i = t; i < NPART; i += 256) v += partials[i];
#pragma unroll
    for (int o = 32; o > 0; o >>= 1)
        v += __shfl_down(v, o, 64);
    if ((t & 63) == 0) wsum[t >> 6] = v;
    __syncthreads();
    if (t == 0)
        out[0] = 1.0f - ((wsum[0] + wsum[1]) + (wsum[2] + wsum[3])) / TOTAL_OUT;
}

extern "C" void kernel_launch(void* const* d_in, const int* in_sizes, int n_in,
                              void* d_out, int out_size, void* d_ws, size_t ws_size,
                              hipStream_t stream) {
    const float* X = (const float*)d_in[0];
    const float* Y = (const float*)d_in[1];
    float* partials = (float*)d_ws;          // NPART floats (8.2 KB)
    float* out = (float*)d_out;

    hipLaunchKernelGGL(ssim_main, dim3(NBLK), dim3(256), 0, stream,
                       X, Y, partials);
    hipLaunchKernelGGL(ssim_finalize, dim3(1), dim3(256), 0, stream,
                       partials, out);
}